// Round 1
// baseline (201.764 us; speedup 1.0000x reference)
//
#include <hip/hip_runtime.h>
#include <stdint.h>

typedef __attribute__((ext_vector_type(8))) short bf16x8;
typedef __attribute__((ext_vector_type(4))) float f32x4;

static __device__ __forceinline__ unsigned short f2bf(float f) {
    unsigned int u = __float_as_uint(f);
    u = u + 0x7FFFu + ((u >> 16) & 1u);   // round-to-nearest-even
    return (unsigned short)(u >> 16);
}

// ---- CSR build ------------------------------------------------------------

__global__ void k_hist(const int* __restrict__ tgt, int* __restrict__ cnt, int E) {
    int e = blockIdx.x * blockDim.x + threadIdx.x;
    if (e < E) atomicAdd(&cnt[tgt[e]], 1);
}

// single-block exclusive scan over cnt[N] -> row_ptr[N+1]; N <= 10240
__global__ void k_scan(const int* __restrict__ cnt, int* __restrict__ row_ptr, int N) {
    __shared__ int sdata[1024];
    const int tid = threadIdx.x;
    const int CH = 10;
    int base = tid * CH;
    int local[CH];
    int sum = 0;
#pragma unroll
    for (int j = 0; j < CH; ++j) {
        int idx = base + j;
        int v = (idx < N) ? cnt[idx] : 0;
        local[j] = sum;
        sum += v;
    }
    sdata[tid] = sum;
    __syncthreads();
    for (int off = 1; off < 1024; off <<= 1) {
        int v = 0;
        if (tid >= off) v = sdata[tid - off];
        __syncthreads();
        if (tid >= off) sdata[tid] += v;
        __syncthreads();
    }
    int excl = sdata[tid] - sum;   // exclusive prefix of this chunk
#pragma unroll
    for (int j = 0; j < CH; ++j) {
        int idx = base + j;
        if (idx < N) row_ptr[idx] = excl + local[j];
    }
    if (tid == 1023) row_ptr[N] = sdata[1023];
}

__global__ void k_dinv(const int* __restrict__ cnt, float* __restrict__ dinv, int N) {
    int i = blockIdx.x * blockDim.x + threadIdx.x;
    if (i < N) dinv[i] = rsqrtf((float)(cnt[i] + 1));   // +1 self-loop
}

__global__ void k_fill(const int* __restrict__ src, const int* __restrict__ tgt,
                       const int* __restrict__ row_ptr, int* __restrict__ fillc,
                       int* __restrict__ esrc, int E) {
    int e = blockIdx.x * blockDim.x + threadIdx.x;
    if (e < E) {
        int t = tgt[e];
        int pos = row_ptr[t] + atomicAdd(&fillc[t], 1);
        esrc[pos] = src[e];
    }
}

// ---- dtype conversion -----------------------------------------------------

__global__ void k_conv_x(const float* __restrict__ x, unsigned short* __restrict__ xb, int total4) {
    int i = blockIdx.x * blockDim.x + threadIdx.x;
    if (i < total4) {
        float4 v = ((const float4*)x)[i];
        ushort4 o;
        o.x = f2bf(v.x); o.y = f2bf(v.y); o.z = f2bf(v.z); o.w = f2bf(v.w);
        ((ushort4*)xb)[i] = o;
    }
}

// W[K][Nc] fp32 -> Wt[Nc][K] bf16
__global__ void k_transpose_w(const float* __restrict__ W, unsigned short* __restrict__ Wt,
                              int K, int Nc) {
    int idx = blockIdx.x * blockDim.x + threadIdx.x;
    if (idx < K * Nc) {
        int n = idx / K, k = idx - n * K;
        Wt[idx] = f2bf(W[(size_t)k * Nc + n]);
    }
}

// ---- bf16 MFMA GEMM: C[M,N] = A[M,K] * Bt[N,K]^T --------------------------
// block = 256 threads (4 waves); block tile 64 rows x 64 cols;
// wave w owns rows [rowbase + 16w, +16), 4 accumulators of 16x16 across cols.

__global__ __launch_bounds__(256) void k_gemm_bf16(
    const short* __restrict__ A,   // [M,K] row-major bf16 bits
    const short* __restrict__ Bt,  // [N,K] row-major bf16 bits (B transposed)
    float* __restrict__ C,         // [M,N] fp32
    int M, int N, int K)
{
    const int lane = threadIdx.x & 63;
    const int wave = threadIdx.x >> 6;
    const int rowbase = blockIdx.x * 64 + wave * 16;
    const int colbase = blockIdx.y * 64;

    const int arow = rowbase + (lane & 15);
    const int koff = (lane >> 4) * 8;
    const bool avalid = (arow < M);

    const short* aptr  = A + (size_t)(avalid ? arow : 0) * K + koff;
    const short* bptr0 = Bt + (size_t)(colbase + (lane & 15)) * K + koff;
    const short* bptr1 = bptr0 + (size_t)16 * K;
    const short* bptr2 = bptr0 + (size_t)32 * K;
    const short* bptr3 = bptr0 + (size_t)48 * K;

    f32x4 acc0 = {0.f, 0.f, 0.f, 0.f};
    f32x4 acc1 = acc0, acc2 = acc0, acc3 = acc0;

    for (int k0 = 0; k0 < K; k0 += 32) {
        bf16x8 af = *(const bf16x8*)(aptr + k0);
        bf16x8 b0 = *(const bf16x8*)(bptr0 + k0);
        bf16x8 b1 = *(const bf16x8*)(bptr1 + k0);
        bf16x8 b2 = *(const bf16x8*)(bptr2 + k0);
        bf16x8 b3 = *(const bf16x8*)(bptr3 + k0);
        acc0 = __builtin_amdgcn_mfma_f32_16x16x32_bf16(af, b0, acc0, 0, 0, 0);
        acc1 = __builtin_amdgcn_mfma_f32_16x16x32_bf16(af, b1, acc1, 0, 0, 0);
        acc2 = __builtin_amdgcn_mfma_f32_16x16x32_bf16(af, b2, acc2, 0, 0, 0);
        acc3 = __builtin_amdgcn_mfma_f32_16x16x32_bf16(af, b3, acc3, 0, 0, 0);
    }

    // C/D layout: col = lane&15, row = (lane>>4)*4 + i   [m89-verified]
    const int crow0 = rowbase + (lane >> 4) * 4;
    const int ccol  = colbase + (lane & 15);
#pragma unroll
    for (int i = 0; i < 4; ++i) {
        int r = crow0 + i;
        if (r < M) {
            float* cp = C + (size_t)r * N + ccol;
            cp[0]  = acc0[i];
            cp[16] = acc1[i];
            cp[32] = acc2[i];
            cp[48] = acc3[i];
        }
    }
}

// ---- aggregation ----------------------------------------------------------
// layer 1: h[t] = ( dinv[t] * (sum_{s->t} dinv[s]*xw[s] + dinv[t]*xw[t]) )^2 -> bf16
// one block per node, 256 threads x 2 cols (D=512)

__global__ __launch_bounds__(256) void k_agg1(
    const float* __restrict__ xw, const int* __restrict__ row_ptr,
    const int* __restrict__ esrc, const float* __restrict__ dinv,
    unsigned int* __restrict__ hb /* packed 2x bf16 */, int Nn)
{
    int t = blockIdx.x;
    if (t >= Nn) return;
    const int c = threadIdx.x;   // float2 column index
    float dt = dinv[t];
    float2 v = ((const float2*)(xw + (size_t)t * 512))[c];
    float ax = dt * v.x, ay = dt * v.y;

    int e = row_ptr[t], e1 = row_ptr[t + 1];
    for (; e + 1 < e1; e += 2) {
        int s0 = esrc[e], s1 = esrc[e + 1];
        float w0 = dinv[s0], w1 = dinv[s1];
        float2 u0 = ((const float2*)(xw + (size_t)s0 * 512))[c];
        float2 u1 = ((const float2*)(xw + (size_t)s1 * 512))[c];
        ax += w0 * u0.x + w1 * u1.x;
        ay += w0 * u0.y + w1 * u1.y;
    }
    if (e < e1) {
        int s = esrc[e];
        float w = dinv[s];
        float2 u = ((const float2*)(xw + (size_t)s * 512))[c];
        ax += w * u.x;
        ay += w * u.y;
    }
    float rx = dt * ax, ry = dt * ay;
    rx *= rx; ry *= ry;                       // squared activation
    hb[(size_t)t * 256 + c] = ((unsigned int)f2bf(ry) << 16) | (unsigned int)f2bf(rx);
}

// layer 2: out[t] = dinv[t] * (sum dinv[s]*xw2[s] + dinv[t]*xw2[t]), D=256, fp32 out
__global__ __launch_bounds__(256) void k_agg2(
    const float* __restrict__ xw, const int* __restrict__ row_ptr,
    const int* __restrict__ esrc, const float* __restrict__ dinv,
    float* __restrict__ out, int Nn)
{
    int t = blockIdx.x;
    if (t >= Nn) return;
    const int c = threadIdx.x;
    float dt = dinv[t];
    float acc = dt * xw[(size_t)t * 256 + c];

    int e = row_ptr[t], e1 = row_ptr[t + 1];
    for (; e + 1 < e1; e += 2) {
        int s0 = esrc[e], s1 = esrc[e + 1];
        float w0 = dinv[s0], w1 = dinv[s1];
        acc += w0 * xw[(size_t)s0 * 256 + c] + w1 * xw[(size_t)s1 * 256 + c];
    }
    if (e < e1) {
        int s = esrc[e];
        acc += dinv[s] * xw[(size_t)s * 256 + c];
    }
    out[(size_t)t * 256 + c] = dt * acc;
}

// ---- launch ---------------------------------------------------------------

extern "C" void kernel_launch(void* const* d_in, const int* in_sizes, int n_in,
                              void* d_out, int out_size, void* d_ws, size_t ws_size,
                              hipStream_t stream) {
    const float* x   = (const float*)d_in[0];
    const int*  eidx = (const int*)d_in[1];
    const float* W1  = (const float*)d_in[2];
    const float* W2  = (const float*)d_in[3];
    float* out = (float*)d_out;

    const int DIN = 512, DHID = 512, DOUT = 256;
    const int Nn = in_sizes[0] / DIN;   // 10000
    const int E  = in_sizes[1] / 2;     // 160000
    const int* src = eidx;
    const int* tgt = eidx + E;

    char* ws = (char*)d_ws;
    size_t off = 0;
    auto alloc = [&](size_t bytes) -> char* {
        off = (off + 255) & ~(size_t)255;
        char* p = ws + off;
        off += bytes;
        return p;
    };

    int*   cnt     = (int*)  alloc((size_t)Nn * 4);
    int*   row_ptr = (int*)  alloc((size_t)(Nn + 1) * 4);
    int*   fillc   = (int*)  alloc((size_t)Nn * 4);
    float* dinv    = (float*)alloc((size_t)Nn * 4);
    int*   esrc    = (int*)  alloc((size_t)E * 4);
    unsigned short* xb  = (unsigned short*)alloc((size_t)Nn * DIN * 2);
    unsigned short* w1t = (unsigned short*)alloc((size_t)DIN * DHID * 2);
    unsigned short* w2t = (unsigned short*)alloc((size_t)DHID * DOUT * 2);
    float* xw = (float*)alloc((size_t)Nn * DHID * 4);   // reused for layer-2 (Nn*DOUT)
    unsigned short* hb = (unsigned short*)alloc((size_t)Nn * DHID * 2);

    hipMemsetAsync(cnt, 0, (size_t)Nn * 4, stream);
    hipMemsetAsync(fillc, 0, (size_t)Nn * 4, stream);

    k_hist<<<(E + 255) / 256, 256, 0, stream>>>(tgt, cnt, E);
    k_scan<<<1, 1024, 0, stream>>>(cnt, row_ptr, Nn);
    k_dinv<<<(Nn + 255) / 256, 256, 0, stream>>>(cnt, dinv, Nn);
    k_fill<<<(E + 255) / 256, 256, 0, stream>>>(src, tgt, row_ptr, fillc, esrc, E);

    int total4 = Nn * DIN / 4;
    k_conv_x<<<(total4 + 255) / 256, 256, 0, stream>>>(x, xb, total4);
    k_transpose_w<<<(DIN * DHID + 255) / 256, 256, 0, stream>>>(W1, w1t, DIN, DHID);
    k_transpose_w<<<(DHID * DOUT + 255) / 256, 256, 0, stream>>>(W2, w2t, DHID, DOUT);

    // layer 1
    k_gemm_bf16<<<dim3((Nn + 63) / 64, DHID / 64), 256, 0, stream>>>(
        (const short*)xb, (const short*)w1t, xw, Nn, DHID, DIN);
    k_agg1<<<Nn, 256, 0, stream>>>(xw, row_ptr, esrc, dinv, (unsigned int*)hb, Nn);

    // layer 2 (reuse xw buffer)
    k_gemm_bf16<<<dim3((Nn + 63) / 64, DOUT / 64), 256, 0, stream>>>(
        (const short*)hb, (const short*)w2t, xw, Nn, DOUT, DHID);
    k_agg2<<<Nn, 256, 0, stream>>>(xw, row_ptr, esrc, dinv, out, Nn);
}

// Round 2
// 124.696 us; speedup vs baseline: 1.6181x; 1.6181x over previous
//
#include <hip/hip_runtime.h>
#include <stdint.h>

typedef __attribute__((ext_vector_type(8))) short bf16x8;
typedef __attribute__((ext_vector_type(4))) float f32x4;

static __device__ __forceinline__ unsigned short f2bf(float f) {
    unsigned int u = __float_as_uint(f);
    u = u + 0x7FFFu + ((u >> 16) & 1u);   // round-to-nearest-even
    return (unsigned short)(u >> 16);
}
static __device__ __forceinline__ float bf2f(short b) {
    return __uint_as_float(((unsigned int)(unsigned short)b) << 16);
}

#define GLD_LDS16(g, l) __builtin_amdgcn_global_load_lds( \
    (const __attribute__((address_space(1))) uint32_t*)(g), \
    (__attribute__((address_space(3))) uint32_t*)(l), 16, 0, 0)

// ---- CSR build ------------------------------------------------------------

__global__ void k_hist(const int* __restrict__ tgt, int* __restrict__ cnt, int E) {
    int e = blockIdx.x * blockDim.x + threadIdx.x;
    if (e < E) atomicAdd(&cnt[tgt[e]], 1);
}

// single-block exclusive scan over cnt[N] -> row_ptr[N+1]; N <= 10240
__global__ void k_scan(const int* __restrict__ cnt, int* __restrict__ row_ptr, int N) {
    __shared__ int sdata[1024];
    const int tid = threadIdx.x;
    const int CH = 10;
    int base = tid * CH;
    int local[CH];
    int sum = 0;
#pragma unroll
    for (int j = 0; j < CH; ++j) {
        int idx = base + j;
        int v = (idx < N) ? cnt[idx] : 0;
        local[j] = sum;
        sum += v;
    }
    sdata[tid] = sum;
    __syncthreads();
    for (int off = 1; off < 1024; off <<= 1) {
        int v = 0;
        if (tid >= off) v = sdata[tid - off];
        __syncthreads();
        if (tid >= off) sdata[tid] += v;
        __syncthreads();
    }
    int excl = sdata[tid] - sum;
#pragma unroll
    for (int j = 0; j < CH; ++j) {
        int idx = base + j;
        if (idx < N) row_ptr[idx] = excl + local[j];
    }
    if (tid == 1023) row_ptr[N] = sdata[1023];
}

__global__ void k_dinv(const int* __restrict__ cnt, float* __restrict__ dinv, int N) {
    int i = blockIdx.x * blockDim.x + threadIdx.x;
    if (i < N) dinv[i] = rsqrtf((float)(cnt[i] + 1));
}

__global__ void k_fill(const int* __restrict__ src, const int* __restrict__ tgt,
                       const int* __restrict__ row_ptr, int* __restrict__ fillc,
                       int* __restrict__ esrc, int E) {
    int e = blockIdx.x * blockDim.x + threadIdx.x;
    if (e < E) {
        int t = tgt[e];
        int pos = row_ptr[t] + atomicAdd(&fillc[t], 1);
        esrc[pos] = src[e];
    }
}

// ---- dtype conversion -----------------------------------------------------

__global__ void k_conv_x(const float* __restrict__ x, unsigned short* __restrict__ xb, int total4) {
    int i = blockIdx.x * blockDim.x + threadIdx.x;
    if (i < total4) {
        float4 v = ((const float4*)x)[i];
        ushort4 o;
        o.x = f2bf(v.x); o.y = f2bf(v.y); o.z = f2bf(v.z); o.w = f2bf(v.w);
        ((ushort4*)xb)[i] = o;
    }
}

// W[K][Nc] fp32 -> Wt[Nc][K] bf16
__global__ void k_transpose_w(const float* __restrict__ W, unsigned short* __restrict__ Wt,
                              int K, int Nc) {
    int idx = blockIdx.x * blockDim.x + threadIdx.x;
    if (idx < K * Nc) {
        int n = idx / K, k = idx - n * K;
        Wt[idx] = f2bf(W[(size_t)k * Nc + n]);
    }
}

// ---- bf16 MFMA GEMM: C[M,N] = A[M,K] * Bt[N,K]^T --------------------------
// 64x64 block tile, BK=64, 4 waves each computing a 32x32 quadrant.
// global_load_lds(16B) staging, LDS [64][64] bf16 with XOR slot swizzle
// (slot ^= row&7) applied on BOTH the pre-swizzled global source and the
// ds_read address (rule #21).

template<bool OUT_BF16>
__global__ __launch_bounds__(256) void k_gemm64(
    const short* __restrict__ A,   // [M,K] bf16 bits
    const short* __restrict__ Bt,  // [N,K] bf16 bits
    void* __restrict__ C,          // [M,N] bf16 or f32
    int M, int N, int K)
{
    __shared__ char smem[16384];   // A tile [0,8K), B tile [8K,16K)
    char* smA = smem;
    char* smB = smem + 8192;

    const int tid  = threadIdx.x;
    const int lane = tid & 63;
    const int wave = tid >> 6;
    const int rowbase = blockIdx.x * 64;
    const int colbase = blockIdx.y * 64;

    // --- staging addresses (pre-swizzled source) ---
    // chunk = call*256 + tid; row = chunk/8 in [0,64), slot = chunk%8 (16B units)
    const int srow0 = tid >> 3;          // call 0: rows 0..31
    const int srow1 = srow0 + 32;        // call 1: rows 32..63
    const int sslot = tid & 7;
    const int scol0 = (sslot ^ (srow0 & 7)) << 3;   // element offset (bf16)
    const int scol1 = (sslot ^ (srow1 & 7)) << 3;   // (srow1&7 == srow0&7)

    int ga0 = rowbase + srow0; if (ga0 >= M) ga0 = M - 1;
    int ga1 = rowbase + srow1; if (ga1 >= M) ga1 = M - 1;
    const size_t offA0 = (size_t)ga0 * K + scol0;
    const size_t offA1 = (size_t)ga1 * K + scol1;
    const size_t offB0 = (size_t)(colbase + srow0) * K + scol0;
    const size_t offB1 = (size_t)(colbase + srow1) * K + scol1;

    char* ldsA0 = smA + wave * 1024;
    char* ldsA1 = smA + 4096 + wave * 1024;
    char* ldsB0 = smB + wave * 1024;
    char* ldsB1 = smB + 4096 + wave * 1024;

    // --- fragment geometry ---
    const int wr = (wave >> 1) * 32;     // wave's row quadrant in tile
    const int wc = (wave & 1) * 32;      // wave's col quadrant
    const int fr = lane & 15;
    const int fs = lane >> 4;            // k-subslot 0..3

    f32x4 acc[2][2];
#pragma unroll
    for (int m = 0; m < 2; ++m)
#pragma unroll
        for (int n = 0; n < 2; ++n)
            acc[m][n] = (f32x4){0.f, 0.f, 0.f, 0.f};

    for (int k0 = 0; k0 < K; k0 += 64) {
        GLD_LDS16(A  + offA0 + k0, ldsA0);
        GLD_LDS16(A  + offA1 + k0, ldsA1);
        GLD_LDS16(Bt + offB0 + k0, ldsB0);
        GLD_LDS16(Bt + offB1 + k0, ldsB1);
        __syncthreads();

        bf16x8 a[2][2], b[2][2];
#pragma unroll
        for (int m = 0; m < 2; ++m)
#pragma unroll
            for (int ks = 0; ks < 2; ++ks) {
                int r = wr + m * 16 + fr;
                int s = ks * 4 + fs;
                a[m][ks] = *(const bf16x8*)(smA + r * 128 + ((s ^ (r & 7)) << 4));
            }
#pragma unroll
        for (int n = 0; n < 2; ++n)
#pragma unroll
            for (int ks = 0; ks < 2; ++ks) {
                int r = wc + n * 16 + fr;
                int s = ks * 4 + fs;
                b[n][ks] = *(const bf16x8*)(smB + r * 128 + ((s ^ (r & 7)) << 4));
            }
#pragma unroll
        for (int m = 0; m < 2; ++m)
#pragma unroll
            for (int n = 0; n < 2; ++n)
#pragma unroll
                for (int ks = 0; ks < 2; ++ks)
                    acc[m][n] = __builtin_amdgcn_mfma_f32_16x16x32_bf16(
                        a[m][ks], b[n][ks], acc[m][n], 0, 0, 0);
        __syncthreads();
    }

    // C/D layout: col = lane&15, row = (lane>>4)*4 + i
    const int orow0 = rowbase + wr + fs * 4;
    const int ocol0 = colbase + wc + fr;
#pragma unroll
    for (int m = 0; m < 2; ++m)
#pragma unroll
        for (int i = 0; i < 4; ++i) {
            int row = orow0 + m * 16 + i;
            if (row < M) {
#pragma unroll
                for (int n = 0; n < 2; ++n) {
                    size_t idx = (size_t)row * N + ocol0 + n * 16;
                    if (OUT_BF16) ((unsigned short*)C)[idx] = f2bf(acc[m][n][i]);
                    else          ((float*)C)[idx] = acc[m][n][i];
                }
            }
        }
}

// ---- aggregation ----------------------------------------------------------
// layer 1: h[t] = ( dinv[t]*(sum dinv[s]*xw[s] + dinv[t]*xw[t]) )^2, bf16 in/out
// one wave per node; lane owns 8 cols (16B vector gathers)

__global__ __launch_bounds__(64) void k_agg1(
    const unsigned short* __restrict__ xwb,   // [Nn][512] bf16
    const int* __restrict__ row_ptr, const int* __restrict__ esrc,
    const float* __restrict__ dinv,
    unsigned short* __restrict__ hb,          // [Nn][512] bf16
    int Nn)
{
    const int t = blockIdx.x;
    const int lane = threadIdx.x;
    const float dt = dinv[t];

    float acc[8];
    bf16x8 v = *(const bf16x8*)(xwb + (size_t)t * 512 + lane * 8);
#pragma unroll
    for (int j = 0; j < 8; ++j) acc[j] = dt * bf2f(v[j]);

    int e = row_ptr[t], e1 = row_ptr[t + 1];
    for (; e + 1 < e1; e += 2) {
        int s0 = esrc[e], s1 = esrc[e + 1];
        float w0 = dinv[s0], w1 = dinv[s1];
        bf16x8 u0 = *(const bf16x8*)(xwb + (size_t)s0 * 512 + lane * 8);
        bf16x8 u1 = *(const bf16x8*)(xwb + (size_t)s1 * 512 + lane * 8);
#pragma unroll
        for (int j = 0; j < 8; ++j) acc[j] += w0 * bf2f(u0[j]) + w1 * bf2f(u1[j]);
    }
    if (e < e1) {
        int s = esrc[e];
        float w = dinv[s];
        bf16x8 u = *(const bf16x8*)(xwb + (size_t)s * 512 + lane * 8);
#pragma unroll
        for (int j = 0; j < 8; ++j) acc[j] += w * bf2f(u[j]);
    }

    bf16x8 o;
#pragma unroll
    for (int j = 0; j < 8; ++j) {
        float r = dt * acc[j];
        r *= r;                               // squared activation
        o[j] = (short)f2bf(r);
    }
    *(bf16x8*)(hb + (size_t)t * 512 + lane * 8) = o;
}

// layer 2: out[t] = dinv[t]*(sum dinv[s]*xw2[s] + dinv[t]*xw2[t]), f32, D=256
__global__ __launch_bounds__(64) void k_agg2(
    const float* __restrict__ xw, const int* __restrict__ row_ptr,
    const int* __restrict__ esrc, const float* __restrict__ dinv,
    float* __restrict__ out, int Nn)
{
    const int t = blockIdx.x;
    const int lane = threadIdx.x;
    const float dt = dinv[t];

    float4 s4 = ((const float4*)(xw + (size_t)t * 256))[lane];
    float a0 = dt * s4.x, a1 = dt * s4.y, a2 = dt * s4.z, a3 = dt * s4.w;

    int e = row_ptr[t], e1 = row_ptr[t + 1];
    for (; e + 1 < e1; e += 2) {
        int s0 = esrc[e], s1 = esrc[e + 1];
        float w0 = dinv[s0], w1 = dinv[s1];
        float4 u0 = ((const float4*)(xw + (size_t)s0 * 256))[lane];
        float4 u1 = ((const float4*)(xw + (size_t)s1 * 256))[lane];
        a0 += w0 * u0.x + w1 * u1.x;
        a1 += w0 * u0.y + w1 * u1.y;
        a2 += w0 * u0.z + w1 * u1.z;
        a3 += w0 * u0.w + w1 * u1.w;
    }
    if (e < e1) {
        int s = esrc[e];
        float w = dinv[s];
        float4 u = ((const float4*)(xw + (size_t)s * 256))[lane];
        a0 += w * u.x; a1 += w * u.y; a2 += w * u.z; a3 += w * u.w;
    }
    float4 r; r.x = dt * a0; r.y = dt * a1; r.z = dt * a2; r.w = dt * a3;
    ((float4*)(out + (size_t)t * 256))[lane] = r;
}

// ---- launch ---------------------------------------------------------------

extern "C" void kernel_launch(void* const* d_in, const int* in_sizes, int n_in,
                              void* d_out, int out_size, void* d_ws, size_t ws_size,
                              hipStream_t stream) {
    const float* x   = (const float*)d_in[0];
    const int*  eidx = (const int*)d_in[1];
    const float* W1  = (const float*)d_in[2];
    const float* W2  = (const float*)d_in[3];
    float* out = (float*)d_out;

    const int DIN = 512, DHID = 512, DOUT = 256;
    const int Nn = in_sizes[0] / DIN;   // 10000
    const int E  = in_sizes[1] / 2;     // 160000
    const int* src = eidx;
    const int* tgt = eidx + E;

    char* ws = (char*)d_ws;
    size_t off = 0;
    auto alloc = [&](size_t bytes) -> char* {
        off = (off + 255) & ~(size_t)255;
        char* p = ws + off;
        off += bytes;
        return p;
    };

    int*   cnt     = (int*)  alloc((size_t)Nn * 4);
    int*   row_ptr = (int*)  alloc((size_t)(Nn + 1) * 4);
    int*   fillc   = (int*)  alloc((size_t)Nn * 4);
    float* dinv    = (float*)alloc((size_t)Nn * 4);
    int*   esrc    = (int*)  alloc((size_t)E * 4);
    unsigned short* xb  = (unsigned short*)alloc((size_t)Nn * DIN * 2);
    unsigned short* w1t = (unsigned short*)alloc((size_t)DIN * DHID * 2);
    unsigned short* w2t = (unsigned short*)alloc((size_t)DHID * DOUT * 2);
    unsigned short* xwb = (unsigned short*)alloc((size_t)Nn * DHID * 2);  // layer-1 GEMM out, bf16
    unsigned short* hb  = (unsigned short*)alloc((size_t)Nn * DHID * 2);  // h, bf16
    float* xw2 = (float*)alloc((size_t)Nn * DOUT * 4);                    // layer-2 GEMM out, f32

    hipMemsetAsync(cnt, 0, (size_t)Nn * 4, stream);
    hipMemsetAsync(fillc, 0, (size_t)Nn * 4, stream);

    k_hist<<<(E + 255) / 256, 256, 0, stream>>>(tgt, cnt, E);
    k_scan<<<1, 1024, 0, stream>>>(cnt, row_ptr, Nn);
    k_dinv<<<(Nn + 255) / 256, 256, 0, stream>>>(cnt, dinv, Nn);
    k_fill<<<(E + 255) / 256, 256, 0, stream>>>(src, tgt, row_ptr, fillc, esrc, E);

    int total4 = Nn * DIN / 4;
    k_conv_x<<<(total4 + 255) / 256, 256, 0, stream>>>(x, xb, total4);
    k_transpose_w<<<(DIN * DHID + 255) / 256, 256, 0, stream>>>(W1, w1t, DIN, DHID);
    k_transpose_w<<<(DHID * DOUT + 255) / 256, 256, 0, stream>>>(W2, w2t, DHID, DOUT);

    // layer 1: xwb = bf16(x @ W1); h = (norm-agg(xwb))^2
    k_gemm64<true><<<dim3((Nn + 63) / 64, DHID / 64), 256, 0, stream>>>(
        (const short*)xb, (const short*)w1t, (void*)xwb, Nn, DHID, DIN);
    k_agg1<<<Nn, 64, 0, stream>>>(xwb, row_ptr, esrc, dinv, hb, Nn);

    // layer 2: xw2 = f32(h @ W2); out = norm-agg(xw2)
    k_gemm64<false><<<dim3((Nn + 63) / 64, DOUT / 64), 256, 0, stream>>>(
        (const short*)hb, (const short*)w2t, (void*)xw2, Nn, DOUT, DHID);
    k_agg2<<<Nn, 64, 0, stream>>>(xw2, row_ptr, esrc, dinv, out, Nn);
}

// Round 3
// 103.671 us; speedup vs baseline: 1.9462x; 1.2028x over previous
//
#include <hip/hip_runtime.h>
#include <stdint.h>

typedef __attribute__((ext_vector_type(8))) short bf16x8;
typedef __attribute__((ext_vector_type(4))) short bf16x4;
typedef __attribute__((ext_vector_type(4))) float f32x4;

static __device__ __forceinline__ unsigned short f2bf(float f) {
    unsigned int u = __float_as_uint(f);
    u = u + 0x7FFFu + ((u >> 16) & 1u);   // round-to-nearest-even
    return (unsigned short)(u >> 16);
}
static __device__ __forceinline__ float bf2f(short b) {
    return __uint_as_float(((unsigned int)(unsigned short)b) << 16);
}

#define GLD_LDS16(g, l) __builtin_amdgcn_global_load_lds( \
    (const __attribute__((address_space(1))) uint32_t*)(g), \
    (__attribute__((address_space(3))) uint32_t*)(l), 16, 0, 0)

// ---- fused setup: hist | conv_x | transpose W1 | transpose W2 -------------
// block ranges: [0,625) hist, [625,5625) conv_x, [5625,6649) tW1, [6649,7161) tW2

__global__ __launch_bounds__(256) void k_setup(
    const int* __restrict__ tgt, int* __restrict__ cnt, int E,
    const float* __restrict__ x, unsigned short* __restrict__ xb, int total4,
    const float* __restrict__ W1, unsigned short* __restrict__ w1t,
    const float* __restrict__ W2, unsigned short* __restrict__ w2t)
{
    const int bid = blockIdx.x;
    const int tid = threadIdx.x;
    if (bid < 625) {                                   // hist
        int e = bid * 256 + tid;
        if (e < E) atomicAdd(&cnt[tgt[e]], 1);
    } else if (bid < 5625) {                           // conv x -> bf16
        int i = (bid - 625) * 256 + tid;
        if (i < total4) {
            float4 v = ((const float4*)x)[i];
            ushort4 o;
            o.x = f2bf(v.x); o.y = f2bf(v.y); o.z = f2bf(v.z); o.w = f2bf(v.w);
            ((ushort4*)xb)[i] = o;
        }
    } else if (bid < 6649) {                           // W1[512][512] -> w1t[n][k]
        int idx = (bid - 5625) * 256 + tid;            // 262144 total
        int n = idx >> 9, k = idx & 511;
        w1t[idx] = f2bf(W1[(size_t)k * 512 + n]);
    } else {                                           // W2[512][256] -> w2t[n][k]
        int idx = (bid - 6649) * 256 + tid;            // 131072 total
        int n = idx >> 9, k = idx & 511;
        w2t[idx] = f2bf(W2[(size_t)k * 256 + n]);
    }
}

// ---- scan (+dinv): single-block exclusive scan cnt[N] -> row_ptr[N+1] -----

__global__ void k_scan(const int* __restrict__ cnt, int* __restrict__ row_ptr,
                       float* __restrict__ dinv, int N) {
    __shared__ int sdata[1024];
    const int tid = threadIdx.x;
    const int CH = 10;
    int base = tid * CH;
    int local[CH];
    int sum = 0;
#pragma unroll
    for (int j = 0; j < CH; ++j) {
        int idx = base + j;
        int v = (idx < N) ? cnt[idx] : 0;
        if (idx < N) dinv[idx] = rsqrtf((float)(v + 1));
        local[j] = sum;
        sum += v;
    }
    sdata[tid] = sum;
    __syncthreads();
    for (int off = 1; off < 1024; off <<= 1) {
        int v = 0;
        if (tid >= off) v = sdata[tid - off];
        __syncthreads();
        if (tid >= off) sdata[tid] += v;
        __syncthreads();
    }
    int excl = sdata[tid] - sum;
#pragma unroll
    for (int j = 0; j < CH; ++j) {
        int idx = base + j;
        if (idx < N) row_ptr[idx] = excl + local[j];
    }
    if (tid == 1023) row_ptr[N] = sdata[1023];
}

__global__ void k_fill(const int* __restrict__ src, const int* __restrict__ tgt,
                       const int* __restrict__ row_ptr, int* __restrict__ fillc,
                       int* __restrict__ esrc, int E) {
    int e = blockIdx.x * blockDim.x + threadIdx.x;
    if (e < E) {
        int t = tgt[e];
        int pos = row_ptr[t] + atomicAdd(&fillc[t], 1);
        esrc[pos] = src[e];
    }
}

// ---- bf16 MFMA GEMM: C[M,N] = bf16( rowscale? dinv[m]*: ) A[M,K] Bt[N,K]^T
// tile 64x128, BK=64, 4 waves (2x2) each owning 32x64; XCD-chunked swizzle.

template<bool SCALE_ROW>
__global__ __launch_bounds__(256) void k_gemm(
    const short* __restrict__ A,   // [M,K] bf16 bits
    const short* __restrict__ Bt,  // [N,K] bf16 bits
    const float* __restrict__ dinv,
    unsigned short* __restrict__ C, // [M,N] bf16
    int M, int N, int K, int ncol, int q, int r)
{
    __shared__ char smem[24576];   // A [64][128B] @0, B [128][128B] @8K
    char* smA = smem;
    char* smB = smem + 8192;

    // bijective XCD-chunked remap (m204): consecutive wg share A rows on one XCD
    const int orig = blockIdx.x;
    const int xcd = orig & 7, loc = orig >> 3;
    const int wg = (xcd < r ? xcd * (q + 1) : r * (q + 1) + (xcd - r) * q) + loc;
    const int rowbase = (wg / ncol) * 64;
    const int colbase = (wg % ncol) * 128;

    const int tid  = threadIdx.x;
    const int lane = tid & 63;
    const int wave = tid >> 6;

    // staging: chunk = call*256+tid; row = chunk>>3, slot = lane&7
    // linear LDS dest, pre-swizzled global col (rule #21)
    const int lrow = (lane >> 3);          // 0..7 within wave's 8-row stripe
    const int scol = ((lane & 7) ^ lrow) << 3;   // element offset in row
    const int rA0 = wave * 8 + lrow;       // call 0 rows 0..31
    int gA0 = rowbase + rA0;          if (gA0 >= M) gA0 = M - 1;
    int gA1 = rowbase + rA0 + 32;     if (gA1 >= M) gA1 = M - 1;
    const size_t offA0 = (size_t)gA0 * K + scol;
    const size_t offA1 = (size_t)gA1 * K + scol;
    size_t offB[4];
#pragma unroll
    for (int c = 0; c < 4; ++c)
        offB[c] = (size_t)(colbase + c * 32 + rA0) * K + scol;

    char* const dA0 = smA + wave * 1024;
    char* const dA1 = smA + 4096 + wave * 1024;
    char* dB[4];
#pragma unroll
    for (int c = 0; c < 4; ++c) dB[c] = smB + c * 4096 + wave * 1024;

    // fragment geometry: wave quadrant 32 rows x 64 cols
    const int wr = (wave >> 1) * 32;
    const int wc = (wave & 1) * 64;
    const int fr = lane & 15;
    const int fs = lane >> 4;

    f32x4 acc[2][4];
#pragma unroll
    for (int m = 0; m < 2; ++m)
#pragma unroll
        for (int n = 0; n < 4; ++n)
            acc[m][n] = (f32x4){0.f, 0.f, 0.f, 0.f};

    for (int k0 = 0; k0 < K; k0 += 64) {
        GLD_LDS16(A + offA0 + k0, dA0);
        GLD_LDS16(A + offA1 + k0, dA1);
#pragma unroll
        for (int c = 0; c < 4; ++c)
            GLD_LDS16(Bt + offB[c] + k0, dB[c]);
        __syncthreads();

        bf16x8 a[2][2], b[4][2];
#pragma unroll
        for (int m = 0; m < 2; ++m)
#pragma unroll
            for (int ks = 0; ks < 2; ++ks) {
                int rr = wr + m * 16 + fr;
                int s = ks * 4 + fs;
                a[m][ks] = *(const bf16x8*)(smA + rr * 128 + ((s ^ (rr & 7)) << 4));
            }
#pragma unroll
        for (int n = 0; n < 4; ++n)
#pragma unroll
            for (int ks = 0; ks < 2; ++ks) {
                int rr = wc + n * 16 + fr;
                int s = ks * 4 + fs;
                b[n][ks] = *(const bf16x8*)(smB + rr * 128 + ((s ^ (rr & 7)) << 4));
            }
#pragma unroll
        for (int m = 0; m < 2; ++m)
#pragma unroll
            for (int n = 0; n < 4; ++n)
#pragma unroll
                for (int ks = 0; ks < 2; ++ks)
                    acc[m][n] = __builtin_amdgcn_mfma_f32_16x16x32_bf16(
                        a[m][ks], b[n][ks], acc[m][n], 0, 0, 0);
        __syncthreads();
    }

    // C/D: col = lane&15, row = fs*4 + i
    const int orow0 = rowbase + wr + fs * 4;
    const int ocol0 = colbase + wc + fr;
#pragma unroll
    for (int m = 0; m < 2; ++m)
#pragma unroll
        for (int i = 0; i < 4; ++i) {
            int row = orow0 + m * 16 + i;
            if (row < M) {
                float sc = SCALE_ROW ? dinv[row] : 1.0f;
#pragma unroll
                for (int n = 0; n < 4; ++n)
                    C[(size_t)row * N + ocol0 + n * 16] = f2bf(sc * acc[m][n][i]);
            }
        }
}

// ---- aggregation ----------------------------------------------------------
// inputs pre-scaled by dinv[src]; pure sums.
// agg1: pre = dt * (sum_{s} u[s] + u[t]); h' = dt * pre^2  -> bf16

__global__ __launch_bounds__(64) void k_agg1(
    const unsigned short* __restrict__ xwb,   // [Nn][512] bf16 (= dinv[s]*xw1[s])
    const int* __restrict__ row_ptr, const int* __restrict__ esrc,
    const float* __restrict__ dinv,
    unsigned short* __restrict__ hb, int Nn)
{
    const int t = blockIdx.x;
    const int lane = threadIdx.x;
    const float dt = dinv[t];

    float acc[8];
    bf16x8 v = *(const bf16x8*)(xwb + (size_t)t * 512 + lane * 8);
#pragma unroll
    for (int j = 0; j < 8; ++j) acc[j] = bf2f(v[j]);

    int e = row_ptr[t], e1 = row_ptr[t + 1];
    for (; e + 3 < e1; e += 4) {
        int s0 = esrc[e], s1 = esrc[e + 1], s2 = esrc[e + 2], s3 = esrc[e + 3];
        bf16x8 u0 = *(const bf16x8*)(xwb + (size_t)s0 * 512 + lane * 8);
        bf16x8 u1 = *(const bf16x8*)(xwb + (size_t)s1 * 512 + lane * 8);
        bf16x8 u2 = *(const bf16x8*)(xwb + (size_t)s2 * 512 + lane * 8);
        bf16x8 u3 = *(const bf16x8*)(xwb + (size_t)s3 * 512 + lane * 8);
#pragma unroll
        for (int j = 0; j < 8; ++j)
            acc[j] += (bf2f(u0[j]) + bf2f(u1[j])) + (bf2f(u2[j]) + bf2f(u3[j]));
    }
    for (; e < e1; ++e) {
        int s = esrc[e];
        bf16x8 u = *(const bf16x8*)(xwb + (size_t)s * 512 + lane * 8);
#pragma unroll
        for (int j = 0; j < 8; ++j) acc[j] += bf2f(u[j]);
    }

    bf16x8 o;
#pragma unroll
    for (int j = 0; j < 8; ++j) {
        float pre = dt * acc[j];
        o[j] = (short)f2bf(dt * pre * pre);   // dinv[t] * h  (pre-scale for layer 2)
    }
    *(bf16x8*)(hb + (size_t)t * 512 + lane * 8) = o;
}

// agg2: out[t] = dt * (sum_s xw2'[s] + xw2'[t]); xw2' bf16 [Nn][256], f32 out
__global__ __launch_bounds__(64) void k_agg2(
    const unsigned short* __restrict__ xwb,   // [Nn][256] bf16 (= dinv[s]*xw2[s])
    const int* __restrict__ row_ptr, const int* __restrict__ esrc,
    const float* __restrict__ dinv,
    float* __restrict__ out, int Nn)
{
    const int t = blockIdx.x;
    const int lane = threadIdx.x;
    const float dt = dinv[t];

    float acc[4];
    bf16x4 v = *(const bf16x4*)(xwb + (size_t)t * 256 + lane * 4);
#pragma unroll
    for (int j = 0; j < 4; ++j) acc[j] = bf2f(v[j]);

    int e = row_ptr[t], e1 = row_ptr[t + 1];
    for (; e + 3 < e1; e += 4) {
        int s0 = esrc[e], s1 = esrc[e + 1], s2 = esrc[e + 2], s3 = esrc[e + 3];
        bf16x4 u0 = *(const bf16x4*)(xwb + (size_t)s0 * 256 + lane * 4);
        bf16x4 u1 = *(const bf16x4*)(xwb + (size_t)s1 * 256 + lane * 4);
        bf16x4 u2 = *(const bf16x4*)(xwb + (size_t)s2 * 256 + lane * 4);
        bf16x4 u3 = *(const bf16x4*)(xwb + (size_t)s3 * 256 + lane * 4);
#pragma unroll
        for (int j = 0; j < 4; ++j)
            acc[j] += (bf2f(u0[j]) + bf2f(u1[j])) + (bf2f(u2[j]) + bf2f(u3[j]));
    }
    for (; e < e1; ++e) {
        int s = esrc[e];
        bf16x4 u = *(const bf16x4*)(xwb + (size_t)s * 256 + lane * 4);
#pragma unroll
        for (int j = 0; j < 4; ++j) acc[j] += bf2f(u[j]);
    }

    float4 rout;
    rout.x = dt * acc[0]; rout.y = dt * acc[1];
    rout.z = dt * acc[2]; rout.w = dt * acc[3];
    ((float4*)(out + (size_t)t * 256))[lane] = rout;
}

// ---- launch ---------------------------------------------------------------

extern "C" void kernel_launch(void* const* d_in, const int* in_sizes, int n_in,
                              void* d_out, int out_size, void* d_ws, size_t ws_size,
                              hipStream_t stream) {
    const float* x   = (const float*)d_in[0];
    const int*  eidx = (const int*)d_in[1];
    const float* W1  = (const float*)d_in[2];
    const float* W2  = (const float*)d_in[3];
    float* out = (float*)d_out;

    const int DIN = 512, DHID = 512, DOUT = 256;
    const int Nn = in_sizes[0] / DIN;   // 10000
    const int E  = in_sizes[1] / 2;     // 160000
    const int* src = eidx;
    const int* tgt = eidx + E;

    char* ws = (char*)d_ws;
    size_t off = 0;
    auto alloc = [&](size_t bytes) -> char* {
        off = (off + 255) & ~(size_t)255;
        char* p = ws + off;
        off += bytes;
        return p;
    };

    int*   cnt     = (int*)  alloc((size_t)Nn * 4);
    int*   row_ptr = (int*)  alloc((size_t)(Nn + 1) * 4);
    int*   fillc   = (int*)  alloc((size_t)Nn * 4);
    float* dinv    = (float*)alloc((size_t)Nn * 4);
    int*   esrc    = (int*)  alloc((size_t)E * 4);
    unsigned short* xb   = (unsigned short*)alloc((size_t)Nn * DIN * 2);
    unsigned short* w1t  = (unsigned short*)alloc((size_t)DIN * DHID * 2);
    unsigned short* w2t  = (unsigned short*)alloc((size_t)DHID * DOUT * 2);
    unsigned short* xwb  = (unsigned short*)alloc((size_t)Nn * DHID * 2);  // dinv*x@W1, bf16
    unsigned short* hb   = (unsigned short*)alloc((size_t)Nn * DHID * 2);  // dinv*h, bf16
    unsigned short* xw2b = (unsigned short*)alloc((size_t)Nn * DOUT * 2);  // dinv*h@W2, bf16

    hipMemsetAsync(cnt, 0, (size_t)Nn * 4, stream);
    hipMemsetAsync(fillc, 0, (size_t)Nn * 4, stream);

    const int total4 = Nn * DIN / 4;
    k_setup<<<7161, 256, 0, stream>>>(tgt, cnt, E, x, xb, total4, W1, w1t, W2, w2t);
    k_scan<<<1, 1024, 0, stream>>>(cnt, row_ptr, dinv, Nn);
    k_fill<<<(E + 255) / 256, 256, 0, stream>>>(src, tgt, row_ptr, fillc, esrc, E);

    // layer 1
    {
        const int nrow = (Nn + 63) / 64, ncol = DHID / 128;
        const int nwg = nrow * ncol;
        k_gemm<true><<<nwg, 256, 0, stream>>>(
            (const short*)xb, (const short*)w1t, dinv, xwb,
            Nn, DHID, DIN, ncol, nwg >> 3, nwg & 7);
    }
    k_agg1<<<Nn, 64, 0, stream>>>(xwb, row_ptr, esrc, dinv, hb, Nn);

    // layer 2
    {
        const int nrow = (Nn + 63) / 64, ncol = DOUT / 128;
        const int nwg = nrow * ncol;
        k_gemm<false><<<nwg, 256, 0, stream>>>(
            (const short*)hb, (const short*)w2t, dinv, xw2b,
            Nn, DOUT, DHID, ncol, nwg >> 3, nwg & 7);
    }
    k_agg2<<<Nn, 64, 0, stream>>>(xw2b, row_ptr, esrc, dinv, out, Nn);
}